// Round 9
// baseline (513.545 us; speedup 1.0000x reference)
//
#include <hip/hip_runtime.h>
#include <hip/hip_bf16.h>

#define VOCAB 512
#define EMB   128
#define HID   64
#define BATCH 256
#define TLEN  1024
#define CH    16              // steps per chunk
#define NCH   (TLEN / CH)     // 64 chunks
#define RS    128             // ring depth in steps (8 chunks)
#define RCH   (RS / CH)       // 8 chunks per ring

typedef float v2f __attribute__((ext_vector_type(2)));

__device__ __forceinline__ float fast_tanh(float x) {
    // tanh(x) = 1 - 2/(exp(2x)+1); exact at both saturated ends.
    float e = __expf(2.0f * x);
    return 1.0f - 2.0f / (e + 1.0f);
}

// 64-lane rotate-by-1 via DPP wave_rol:1 (0x134) — pure VALU on the wave's
// own SIMD: no LDS pipe, no SGPR-write hazard. The rotation DIRECTION is
// irrelevant to correctness: the weight skew below is built by applying the
// SAME op to a lane-index register, so any fixed full-cycle permutation
// yields y[i] = sum over the orbit of i = the complete dot product.
__device__ __forceinline__ int roti(int v) {
    return __builtin_amdgcn_update_dpp(v, v, 0x134, 0xF, 0xF, false);
}
__device__ __forceinline__ float rotf(float v) {
    return __int_as_float(roti(__float_as_int(v)));
}

// Systolic matvec: lane i accumulates the FULL y[i]; h stays distributed
// (lane i holds h[i]) and returns to its home lane after 64 rotations.
// No cross-lane reduce needed. wsk[r] = W[lane][perm^r(lane)].
__device__ __forceinline__ float rotdot(const float* wsk, float h, float init) {
    float a0 = init, a1 = 0.f, a2 = 0.f, a3 = 0.f;
    float hr = h;
    #pragma unroll
    for (int r = 0; r < 64; r += 4) {
        a0 = fmaf(hr, wsk[r + 0], a0); hr = rotf(hr);
        a1 = fmaf(hr, wsk[r + 1], a1); hr = rotf(hr);
        a2 = fmaf(hr, wsk[r + 2], a2); hr = rotf(hr);
        a3 = fmaf(hr, wsk[r + 3], a3); hr = rotf(hr);
    }
    return (a0 + a2) + (a1 + a3);
}

// Broadcast-LDS dot for the non-recurrent projection wave (latency-tolerant).
__device__ __forceinline__ float dot64_lds(const float4* hp, const v2f* w,
                                           float init) {
    v2f a0 = v2f{init, 0.f}, a1 = v2f{0.f, 0.f};
    v2f a2 = v2f{0.f, 0.f},  a3 = v2f{0.f, 0.f};
    #pragma unroll
    for (int q = 0; q < 8; ++q) {
        float4 u = hp[2 * q];
        float4 v = hp[2 * q + 1];
        a0 = __builtin_elementwise_fma(v2f{u.x, u.y}, w[4 * q + 0], a0);
        a1 = __builtin_elementwise_fma(v2f{u.z, u.w}, w[4 * q + 1], a1);
        a2 = __builtin_elementwise_fma(v2f{v.x, v.y}, w[4 * q + 2], a2);
        a3 = __builtin_elementwise_fma(v2f{v.z, v.w}, w[4 * q + 3], a3);
    }
    return ((a0.x + a0.y) + (a1.x + a1.y)) + ((a2.x + a2.y) + (a3.x + a3.y));
}

__device__ __forceinline__ void lds_fence() {
    asm volatile("s_waitcnt lgkmcnt(0)" ::: "memory");
}
__device__ __forceinline__ void compiler_fence() {
    asm volatile("" ::: "memory");
}
__device__ __forceinline__ void nap() { __builtin_amdgcn_s_sleep(1); }

// ---------------------------------------------------------------------------
// Kernel 1: P0[v][i] = sum_e emb[v][e]*Wih0[i][e] + bih0[i] + bhh0[i]  (fp32)
// ---------------------------------------------------------------------------
__global__ void __launch_bounds__(64) p0_kernel(
    const float* __restrict__ emb,
    const float* __restrict__ wih0,
    const float* __restrict__ bih0,
    const float* __restrict__ bhh0,
    float* __restrict__ P0)
{
    const int v = blockIdx.x;
    const int i = threadIdx.x;
    const float4* er = (const float4*)(emb  + v * EMB);
    const float4* wr = (const float4*)(wih0 + i * EMB);
    float a0 = 0.f, a1 = 0.f, a2 = 0.f, a3 = 0.f;
    #pragma unroll
    for (int k = 0; k < EMB / 4; ++k) {
        float4 e4 = er[k];
        float4 w4 = wr[k];
        a0 = fmaf(e4.x, w4.x, a0);
        a1 = fmaf(e4.y, w4.y, a1);
        a2 = fmaf(e4.z, w4.z, a2);
        a3 = fmaf(e4.w, w4.w, a3);
    }
    P0[v * HID + i] = (a0 + a1) + (a2 + a3) + bih0[i] + bhh0[i];
}

// ---------------------------------------------------------------------------
// Kernel 2: 4-wave decoupled pipeline; recurrent waves use DPP rotation
// (zero LDS in the recurrence chain — R5..R8 showed the LDS write->read
// broadcast roundtrip + contention is a ~740 cyc/step floor).
//   wave0: h0[t] = tanh(a0[t] + Whh0 h0[t-1])   DPP systolic, h0 in 1 VGPR
//   wave1: p1[t] = b1 + Wih1 h0[t]               LDS-broadcast dot (no recur)
//   wave2: h1[t] = tanh(p1[t] + Whh1 h1[t-1])   DPP systolic + MLP head
//   wave3: a0[t] = P0[x[t]]  gather -> LDS ring  (keeps global loads out of
//                                                 every recurrent wave)
// Sync: per-chunk LDS flags + lgkmcnt-only fences; no barriers in the loop.
// ---------------------------------------------------------------------------
__global__ void __launch_bounds__(256, 1) rnn_kernel(
    const int*   __restrict__ xs,
    const float* __restrict__ P0,
    const float* __restrict__ Whh0,
    const float* __restrict__ Wih1,
    const float* __restrict__ Whh1,
    const float* __restrict__ bih1,
    const float* __restrict__ bhh1,
    const float* __restrict__ W1,
    const float* __restrict__ b1,
    const float* __restrict__ W2,
    const float* __restrict__ b2,
    float*       __restrict__ out)
{
    __shared__ float a0ring[RS][HID];   // 32 KiB  P0 rows (w3 -> w0)
    __shared__ float h0ring[RS][HID];   // 32 KiB  h0      (w0 -> w1)
    __shared__ float p1ring[RS][HID];   // 32 KiB  p1      (w1 -> w2)
    __shared__ float hN[HID];
    __shared__ int   flags[4];          // completed chunks per wave

    const int b    = blockIdx.x;
    const int tid  = threadIdx.x;
    const int wv   = tid >> 6;
    const int lane = tid & 63;

    const int* xrow = xs + b * TLEN;

    if (tid < 4) flags[tid] = 0;
    __syncthreads();                     // the ONLY barrier in the kernel

    volatile int* vf = (volatile int*)flags;

    if (wv == 3) {
        // ---- P0 gather wave: a0ring[t] = P0[x[t]] ----
        #pragma unroll 1
        for (int k = 0; k < NCH; ++k) {
            if (k >= RCH) {
                while (vf[0] < k - (RCH - 1)) nap();
                compiler_fence();
            }
            const int base = (k & (RCH - 1)) * CH;
            #pragma unroll
            for (int i = 0; i < CH; ++i) {
                const int xv = xrow[k * CH + i];
                a0ring[base + i][lane] = P0[xv * HID + lane];
            }
            lds_fence();
            if (lane == 0) vf[3] = k + 1;
        }
    } else if (wv == 0) {
        // ---- layer-0 recurrence (DPP systolic) ----
        // skewed weights: wsk[r] = Whh0[lane][perm^r(lane)], perm = roti
        float wsk[64];
        {
            int cs[64];
            int c = lane;
            #pragma unroll
            for (int r = 0; r < 64; ++r) { cs[r] = c; c = roti(c); }
            #pragma unroll
            for (int r = 0; r < 64; ++r) wsk[r] = Whh0[lane * HID + cs[r]];
        }
        float h0v = 0.f;
        #pragma unroll 1
        for (int k = 0; k < NCH; ++k) {
            while (vf[3] < k + 1) nap();
            if (k >= RCH) { while (vf[1] < k - (RCH - 1)) nap(); }
            compiler_fence();
            const int base = (k & (RCH - 1)) * CH;
            float av = a0ring[base][lane];
            #pragma unroll 1
            for (int i = 0; i < CH; ++i) {
                // prefetch next step's a0 (1 DS read, consumed next iter)
                const int nx = (i + 1 < CH) ? (i + 1) : i;
                float nv = a0ring[base + nx][lane];
                h0v = fast_tanh(rotdot(wsk, h0v, av));
                h0ring[base + i][lane] = h0v;      // 1 DS write (off-chain)
                av = nv;
            }
            lds_fence();
            if (lane == 0) vf[0] = k + 1;
        }
    } else if (wv == 1) {
        // ---- layer-1 input projection (LDS broadcast; no recurrence) ----
        v2f w[32];
        {
            const float4* wr = (const float4*)(Wih1 + lane * HID);
            #pragma unroll
            for (int k = 0; k < 16; ++k) {
                float4 u = wr[k];
                w[2 * k]     = v2f{u.x, u.y};
                w[2 * k + 1] = v2f{u.z, u.w};
            }
        }
        const float b1s = bih1[lane] + bhh1[lane];
        #pragma unroll 1
        for (int k = 0; k < NCH; ++k) {
            while (vf[0] < k + 1) nap();
            if (k >= RCH) { while (vf[2] < k - (RCH - 1)) nap(); }
            compiler_fence();
            const int base = (k & (RCH - 1)) * CH;
            #pragma unroll
            for (int i = 0; i < CH; ++i) {
                const float4* hp = (const float4*)h0ring[base + i];
                p1ring[base + i][lane] = dot64_lds(hp, w, b1s);
            }
            lds_fence();
            if (lane == 0) vf[1] = k + 1;
        }
    } else {
        // ---- layer-1 recurrence (DPP systolic) + MLP head ----
        float wsk[64];
        {
            int cs[64];
            int c = lane;
            #pragma unroll
            for (int r = 0; r < 64; ++r) { cs[r] = c; c = roti(c); }
            #pragma unroll
            for (int r = 0; r < 64; ++r) wsk[r] = Whh1[lane * HID + cs[r]];
        }
        float h1v = 0.f;
        #pragma unroll 1
        for (int k = 0; k < NCH; ++k) {
            while (vf[1] < k + 1) nap();
            compiler_fence();
            const int base = (k & (RCH - 1)) * CH;
            float pv = p1ring[base][lane];
            #pragma unroll 1
            for (int i = 0; i < CH; ++i) {
                const int nx = (i + 1 < CH) ? (i + 1) : i;
                float nv = p1ring[base + nx][lane];
                h1v = fast_tanh(rotdot(wsk, h1v, pv));
                pv = nv;
            }
            lds_fence();
            if (lane == 0) vf[2] = k + 1;
        }
        // ---- MLP head: y = relu(h1 @ W1^T + b1) @ W2^T + b2 ----
        hN[lane] = h1v;
        lds_fence();
        float r = 0.f;
        if (lane < 32) {
            float acc = b1[lane];
            const float* w1r = W1 + lane * HID;
            #pragma unroll
            for (int j = 0; j < HID; ++j) acc = fmaf(w1r[j], hN[j], acc);
            r = fmaxf(acc, 0.f) * W2[lane];
        }
        #pragma unroll
        for (int off = 32; off > 0; off >>= 1) r += __shfl_down(r, off);
        if (lane == 0) out[b] = r + b2[0];
    }
}

extern "C" void kernel_launch(void* const* d_in, const int* in_sizes, int n_in,
                              void* d_out, int out_size, void* d_ws, size_t ws_size,
                              hipStream_t stream)
{
    const int*   x    = (const int*)d_in[0];
    const float* emb  = (const float*)d_in[1];
    const float* Wih0 = (const float*)d_in[2];
    const float* Whh0 = (const float*)d_in[3];
    const float* bih0 = (const float*)d_in[4];
    const float* bhh0 = (const float*)d_in[5];
    const float* Wih1 = (const float*)d_in[6];
    const float* Whh1 = (const float*)d_in[7];
    const float* bih1 = (const float*)d_in[8];
    const float* bhh1 = (const float*)d_in[9];
    const float* W1   = (const float*)d_in[10];
    const float* b1   = (const float*)d_in[11];
    const float* W2   = (const float*)d_in[12];
    const float* b2   = (const float*)d_in[13];

    float* P0 = (float*)d_ws;   // 512*64*4 = 128 KiB scratch

    hipLaunchKernelGGL(p0_kernel, dim3(VOCAB), dim3(HID), 0, stream,
                       emb, Wih0, bih0, bhh0, P0);
    hipLaunchKernelGGL(rnn_kernel, dim3(BATCH), dim3(256), 0, stream,
                       x, P0, Whh0, Wih1, Whh1, bih1, bhh1,
                       W1, b1, W2, b2, (float*)d_out);
}

// Round 10
// 410.784 us; speedup vs baseline: 1.2502x; 1.2502x over previous
//
#include <hip/hip_runtime.h>
#include <hip/hip_bf16.h>
#include <hip/hip_fp16.h>

#define VOCAB 512
#define EMB   128
#define HID   64
#define BATCH 256
#define TLEN  1024
#define CH    16              // steps per chunk
#define NCH   (TLEN / CH)     // 64 chunks
#define RS    128             // ring depth in steps (8 chunks)
#define RCH   (RS / CH)       // 8 chunks per ring

typedef float v2f __attribute__((ext_vector_type(2)));

__device__ __forceinline__ float fast_tanh(float x) {
    // tanh(x) = 1 - 2/(exp(2x)+1); exact at both saturated ends.
    float e = __expf(2.0f * x);
    return 1.0f - 2.0f / (e + 1.0f);
}

__device__ __forceinline__ void lds_fence() {
    asm volatile("s_waitcnt lgkmcnt(0)" ::: "memory");
}
__device__ __forceinline__ void compiler_fence() {
    asm volatile("" ::: "memory");
}
__device__ __forceinline__ void nap() { __builtin_amdgcn_s_sleep(1); }

// dword (2 packed fp16) -> v2f
__device__ __forceinline__ v2f h2v(unsigned int u) {
    __half2 h = *(__half2*)&u;
    float2 f = __half22float2(h);
    return v2f{f.x, f.y};
}

// dot(w_row, h_broadcast_fp16) + init. 8 broadcast b128 reads (R8 used 16
// fp32 reads — the 52-DS-ops/step shared-pipe throughput was the ~740
// cyc/step plateau). 4 independent 8-deep v2f accumulator chains as in R8.
__device__ __forceinline__ float dot64_h16(const __half* hrow, const v2f* w,
                                           float init) {
    const uint4* hp = (const uint4*)hrow;
    v2f a0 = v2f{init, 0.f}, a1 = v2f{0.f, 0.f};
    v2f a2 = v2f{0.f, 0.f},  a3 = v2f{0.f, 0.f};
    #pragma unroll
    for (int r = 0; r < 8; ++r) {
        uint4 u = hp[r];
        a0 = __builtin_elementwise_fma(h2v(u.x), w[4 * r + 0], a0);
        a1 = __builtin_elementwise_fma(h2v(u.y), w[4 * r + 1], a1);
        a2 = __builtin_elementwise_fma(h2v(u.z), w[4 * r + 2], a2);
        a3 = __builtin_elementwise_fma(h2v(u.w), w[4 * r + 3], a3);
    }
    return ((a0.x + a0.y) + (a1.x + a1.y)) + ((a2.x + a2.y) + (a3.x + a3.y));
}

// ---------------------------------------------------------------------------
// Kernel 1: P0[v][i] = sum_e emb[v][e]*Wih0[i][e] + bih0[i] + bhh0[i]  (fp32)
// ---------------------------------------------------------------------------
__global__ void __launch_bounds__(64) p0_kernel(
    const float* __restrict__ emb,
    const float* __restrict__ wih0,
    const float* __restrict__ bih0,
    const float* __restrict__ bhh0,
    float* __restrict__ P0)
{
    const int v = blockIdx.x;
    const int i = threadIdx.x;
    const float4* er = (const float4*)(emb  + v * EMB);
    const float4* wr = (const float4*)(wih0 + i * EMB);
    float a0 = 0.f, a1 = 0.f, a2 = 0.f, a3 = 0.f;
    #pragma unroll
    for (int k = 0; k < EMB / 4; ++k) {
        float4 e4 = er[k];
        float4 w4 = wr[k];
        a0 = fmaf(e4.x, w4.x, a0);
        a1 = fmaf(e4.y, w4.y, a1);
        a2 = fmaf(e4.z, w4.z, a2);
        a3 = fmaf(e4.w, w4.w, a3);
    }
    P0[v * HID + i] = (a0 + a1) + (a2 + a3) + bih0[i] + bhh0[i];
}

// ---------------------------------------------------------------------------
// Kernel 2: R8's decoupled 3-wave pipeline, with the h broadcast transported
// through LDS as fp16 (ds_write_b16 per lane; 8 b128 broadcast reads/dot).
// DS ops/step: w0 9 + w1 9 + w2 10 = 28 (R8: 52) — attacks the measured
// shared-DS-pipe throughput floor. State/accumulators/weights stay fp32;
// only the h transport is fp16-rounded (RNE, 2^-11 rel on |h|<=1).
//   wave0: h0[t] = tanh(P0[x[t]] + Whh0 h0[t-1])      (recurrent)
//   wave1: p1[t] = b1 + Wih1 h0[t]                     (no recurrence)
//   wave2: h1[t] = tanh(p1[t] + Whh1 h1[t-1])          (recurrent)
// wave0 keeps R8's chunk-ahead VGPR prefetch of x / P0 rows (vmcnt-only).
// ---------------------------------------------------------------------------
__global__ void __launch_bounds__(192, 1) rnn_kernel(
    const int*   __restrict__ xs,
    const float* __restrict__ P0,
    const float* __restrict__ Whh0,
    const float* __restrict__ Wih1,
    const float* __restrict__ Whh1,
    const float* __restrict__ bih1,
    const float* __restrict__ bhh1,
    const float* __restrict__ W1,
    const float* __restrict__ b1,
    const float* __restrict__ W2,
    const float* __restrict__ b2,
    float*       __restrict__ out)
{
    __shared__ __half h0ring[RS][HID];  // 16 KiB  h0 broadcast (fp16)
    __shared__ float  p1ring[RS][HID];  // 32 KiB  p1 (lane-distributed fp32)
    __shared__ __half h1buf[2][HID];    // h1 broadcast (fp16)
    __shared__ float  hN[HID];          // final h1, exact fp32 for the head
    __shared__ int    flags[3];

    const int b    = blockIdx.x;
    const int tid  = threadIdx.x;
    const int wv   = tid >> 6;
    const int lane = tid & 63;

    const int* xrow = xs + b * TLEN;
    // vz == 0, but opaque to uniformity analysis -> forces VECTOR loads
    // (vmcnt path) for the x reads instead of s_load (lgkmcnt path).
    const int vz = (int)__builtin_amdgcn_mbcnt_lo(0u, 0u);

    if (wv == 0) {
        h0ring[RS - 1][lane] = __float2half(0.f);   // h0[-1] = 0
    } else if (wv == 2) {
        h1buf[0][lane] = __float2half(0.f);         // h1[-1] = 0
        h1buf[1][lane] = __float2half(0.f);
    }
    if (tid < 3) flags[tid] = 0;
    __syncthreads();                     // the ONLY barrier in the kernel

    // Per-wave weight row -> 32 packed v2f (64 VGPRs), loop-invariant
    // (proven register-resident regime, VGPR~88).
    const float* wmat = (wv == 0) ? Whh0 : (wv == 1) ? Wih1 : Whh1;
    v2f w[32];
    {
        const float4* wr = (const float4*)(wmat + lane * HID);
        #pragma unroll
        for (int k = 0; k < 16; ++k) {
            float4 u = wr[k];
            w[2 * k]     = v2f{u.x, u.y};
            w[2 * k + 1] = v2f{u.z, u.w};
        }
    }

    volatile int* vf = (volatile int*)flags;

    if (wv == 0) {
        // ---- layer-0 recurrence, chunk-ahead VGPR prefetch pipeline ----
        int   xv_old[CH];
        float a_old[CH];
        #pragma unroll
        for (int i = 0; i < CH; ++i)
            xv_old[i] = xrow[CH + i + vz] & (VOCAB - 1);    // x of chunk 1
        #pragma unroll
        for (int i = 0; i < CH; ++i)
            a_old[i] = P0[(xrow[i + vz] & (VOCAB - 1)) * HID + lane]; // chunk 0

        #pragma unroll 1
        for (int k = 0; k < NCH; ++k) {
            if (k >= RCH) {                       // slot reuse guard
                while (vf[1] < k - (RCH - 1)) nap();
                compiler_fence();
            }
            // prefetch x of chunk k+2 / gather P0 rows of chunk k+1 — all
            // vector loads (vmcnt), consumed a full chunk (>6k cyc) later
            const int  c2  = (k + 2 < NCH) ? (k + 2) : (NCH - 1);
            const int* xp  = xrow + c2 * CH;
            int   xv_new[CH];
            float a_new[CH];
            #pragma unroll
            for (int i = 0; i < CH; ++i)
                xv_new[i] = xp[i + vz] & (VOCAB - 1);
            #pragma unroll
            for (int i = 0; i < CH; ++i)
                a_new[i] = P0[xv_old[i] * HID + lane];

            const int base = (k & (RCH - 1)) * CH;
            #pragma unroll
            for (int i = 0; i < CH; ++i) {
                const __half* hp = h0ring[(base + i - 1) & (RS - 1)];
                float z = dot64_h16(hp, w, a_old[i]);
                h0ring[base + i][lane] = __float2half(fast_tanh(z)); // b16 write
            }
            lds_fence();                          // DS queue only, NOT vmcnt
            if (lane == 0) vf[0] = k + 1;

            #pragma unroll
            for (int i = 0; i < CH; ++i) { a_old[i] = a_new[i]; xv_old[i] = xv_new[i]; }
        }
    } else if (wv == 1) {
        // ---- layer-1 input projection (no recurrence: pure throughput) ----
        const float b1s = bih1[lane] + bhh1[lane];
        #pragma unroll 1
        for (int k = 0; k < NCH; ++k) {
            while (vf[0] < k + 1) nap();
            if (k >= RCH) { while (vf[2] < k - (RCH - 1)) nap(); }
            compiler_fence();
            const int base = (k & (RCH - 1)) * CH;
            #pragma unroll
            for (int i = 0; i < CH; ++i) {
                p1ring[base + i][lane] = dot64_h16(h0ring[base + i], w, b1s);
            }
            lds_fence();
            if (lane == 0) vf[1] = k + 1;
        }
    } else {
        // ---- layer-1 recurrence ----
        #pragma unroll 1
        for (int k = 0; k < NCH; ++k) {
            while (vf[1] < k + 1) nap();
            compiler_fence();
            const int base = (k & (RCH - 1)) * CH;
            float p[CH];                           // bulk chunk prefetch (DS)
            #pragma unroll
            for (int i = 0; i < CH; ++i) p[i] = p1ring[base + i][lane];
            float h1v = 0.f;                       // carried value per lane
            #pragma unroll
            for (int i = 0; i < CH; ++i) {
                const int t = k * CH + i;
                float z = dot64_h16(h1buf[(t + 1) & 1], w, p[i]);
                h1v = fast_tanh(z);
                h1buf[t & 1][lane] = __float2half(h1v);    // b16 write
            }
            lds_fence();                           // p1 reads consumed
            if (lane == 0) vf[2] = k + 1;
            if (k == NCH - 1) { hN[lane] = h1v; }  // exact fp32 for the head
        }
        lds_fence();
        // ---- MLP head: y = relu(h1 @ W1^T + b1) @ W2^T + b2 ----
        float r = 0.f;
        if (lane < 32) {
            float acc = b1[lane];
            const float* w1r = W1 + lane * HID;
            #pragma unroll
            for (int j = 0; j < HID; ++j) acc = fmaf(w1r[j], hN[j], acc);
            r = fmaxf(acc, 0.f) * W2[lane];
        }
        #pragma unroll
        for (int off = 32; off > 0; off >>= 1) r += __shfl_down(r, off);
        if (lane == 0) out[b] = r + b2[0];
    }
}

extern "C" void kernel_launch(void* const* d_in, const int* in_sizes, int n_in,
                              void* d_out, int out_size, void* d_ws, size_t ws_size,
                              hipStream_t stream)
{
    const int*   x    = (const int*)d_in[0];
    const float* emb  = (const float*)d_in[1];
    const float* Wih0 = (const float*)d_in[2];
    const float* Whh0 = (const float*)d_in[3];
    const float* bih0 = (const float*)d_in[4];
    const float* bhh0 = (const float*)d_in[5];
    const float* Wih1 = (const float*)d_in[6];
    const float* Whh1 = (const float*)d_in[7];
    const float* bih1 = (const float*)d_in[8];
    const float* bhh1 = (const float*)d_in[9];
    const float* W1   = (const float*)d_in[10];
    const float* b1   = (const float*)d_in[11];
    const float* W2   = (const float*)d_in[12];
    const float* b2   = (const float*)d_in[13];

    float* P0 = (float*)d_ws;   // 512*64*4 = 128 KiB scratch

    hipLaunchKernelGGL(p0_kernel, dim3(VOCAB), dim3(HID), 0, stream,
                       emb, Wih0, bih0, bhh0, P0);
    hipLaunchKernelGGL(rnn_kernel, dim3(BATCH), dim3(192), 0, stream,
                       x, P0, Whh0, Wih1, Whh1, bih1, bhh1,
                       W1, b1, W2, b2, (float*)d_out);
}